// Round 1
// baseline (22964.619 us; speedup 1.0000x reference)
//
#include <hip/hip_runtime.h>

// Seq2Seq LSTM (B=64, S=T=256, DIN=DOUT=128, H=1024), fp32 baseline.
// Round 1: correctness + overhead measurement. One kernel per recurrence step.
// Decoder feedback folded into Wcomb = dec_Whh + dec_Wih @ fc_W (prep kernel),
// so decoder steps t=1..254 are a single GEMM+cell kernel with the previous
// step's FC output fused as 32 extra blocks.

#define BB   64
#define HH   1024
#define G4   4096
#define DXX  128
#define KC   128
#define SEQN 256
#define TN   256
#define OUT_BSTRIDE (TN * DXX)   // 32768 floats per batch row of the output

__device__ __forceinline__ float sigm(float x)  { return 1.f / (1.f + __expf(-x)); }
__device__ __forceinline__ float tanh_f(float x){ return 1.f - 2.f / (1.f + __expf(2.f * x)); }

// -------- per-step kernel: gates = h@W^T [+ x@Wx^T] + bias; LSTM cell; fused FC --------
// blocks [0, nGates):          gate blocks, 4 hidden indices each (16 W rows)
// blocks [nGates, nGates+32):  FC blocks (pred = h_in @ fcW^T + fcb), 4 outputs each
__global__ __launch_bounds__(256)
void step_kernel(const float* __restrict__ W,      // [4096][1024]
                 const float* __restrict__ Wx,     // [4096][128] or nullptr
                 const float* __restrict__ x,      // [64][xstride] or nullptr
                 int xstride,
                 const float* __restrict__ bias,   // [4096]
                 const float* __restrict__ h_in,   // [64][1024]
                 float* __restrict__ c,            // [64][1024]
                 float* __restrict__ h_out,        // [64][1024]
                 int nGates,
                 const float* __restrict__ fcW,    // [128][1024] or nullptr
                 const float* __restrict__ fcb,    // [128]
                 float* __restrict__ fc_out,       // d_out + t*128 (b-stride 32768) or nullptr
                 float* __restrict__ predbuf)      // [64][128] or nullptr
{
    __shared__ float hT[KC][BB + 1];   // transposed h chunk, padded: conflict-free
    __shared__ float wl[16][KC];       // weight rows for this block

    const int t   = threadIdx.x;
    const int b   = t & 63;
    const int q   = t >> 6;            // 0..3
    const int col = t & (KC - 1);
    const int r0  = t >> 7;            // 0..1
    const int bi  = blockIdx.x;

    if (bi < nGates) {
        const int n0 = bi * 4;
        const int n  = n0 + q;
        float a0 = bias[n];
        float a1 = bias[HH + n];
        float a2 = bias[2 * HH + n];
        float a3 = bias[3 * HH + n];

        for (int k0 = 0; k0 < HH; k0 += KC) {
            #pragma unroll
            for (int rr = 0; rr < BB; rr += 2)
                hT[col][rr + r0] = h_in[(rr + r0) * HH + k0 + col];
            #pragma unroll
            for (int rr = 0; rr < 16; rr += 2) {
                const int r = rr + r0;                    // r = nn*4 + g
                const int j = (r & 3) * HH + n0 + (r >> 2);
                wl[r][col] = W[(size_t)j * HH + k0 + col];
            }
            __syncthreads();
            #pragma unroll 8
            for (int k = 0; k < KC; k += 4) {
                const float4 w0 = *reinterpret_cast<const float4*>(&wl[q * 4 + 0][k]);
                const float4 w1 = *reinterpret_cast<const float4*>(&wl[q * 4 + 1][k]);
                const float4 w2 = *reinterpret_cast<const float4*>(&wl[q * 4 + 2][k]);
                const float4 w3 = *reinterpret_cast<const float4*>(&wl[q * 4 + 3][k]);
                const float h0v = hT[k][b], h1v = hT[k + 1][b];
                const float h2v = hT[k + 2][b], h3v = hT[k + 3][b];
                a0 += h0v * w0.x + h1v * w0.y + h2v * w0.z + h3v * w0.w;
                a1 += h0v * w1.x + h1v * w1.y + h2v * w1.z + h3v * w1.w;
                a2 += h0v * w2.x + h1v * w2.y + h2v * w2.z + h3v * w2.w;
                a3 += h0v * w3.x + h1v * w3.y + h2v * w3.z + h3v * w3.w;
            }
            __syncthreads();
        }

        if (Wx != nullptr) {   // input projection, K = 128 (one chunk)
            #pragma unroll
            for (int rr = 0; rr < BB; rr += 2)
                hT[col][rr + r0] = x[(size_t)(rr + r0) * xstride + col];
            #pragma unroll
            for (int rr = 0; rr < 16; rr += 2) {
                const int r = rr + r0;
                const int j = (r & 3) * HH + n0 + (r >> 2);
                wl[r][col] = Wx[(size_t)j * DXX + col];
            }
            __syncthreads();
            #pragma unroll 8
            for (int k = 0; k < DXX; k += 4) {
                const float4 w0 = *reinterpret_cast<const float4*>(&wl[q * 4 + 0][k]);
                const float4 w1 = *reinterpret_cast<const float4*>(&wl[q * 4 + 1][k]);
                const float4 w2 = *reinterpret_cast<const float4*>(&wl[q * 4 + 2][k]);
                const float4 w3 = *reinterpret_cast<const float4*>(&wl[q * 4 + 3][k]);
                const float h0v = hT[k][b], h1v = hT[k + 1][b];
                const float h2v = hT[k + 2][b], h3v = hT[k + 3][b];
                a0 += h0v * w0.x + h1v * w0.y + h2v * w0.z + h3v * w0.w;
                a1 += h0v * w1.x + h1v * w1.y + h2v * w1.z + h3v * w1.w;
                a2 += h0v * w2.x + h1v * w2.y + h2v * w2.z + h3v * w2.w;
                a3 += h0v * w3.x + h1v * w3.y + h2v * w3.z + h3v * w3.w;
            }
        }

        // LSTM cell (PyTorch gate order i, f, g, o)
        const int ci = b * HH + n;
        const float iv = sigm(a0);
        const float fv = sigm(a1);
        const float gv = tanh_f(a2);
        const float ov = sigm(a3);
        const float cv = fv * c[ci] + iv * gv;
        c[ci]     = cv;
        h_out[ci] = ov * tanh_f(cv);

    } else if (fcW != nullptr && bi < nGates + 32) {
        const int d0 = (bi - nGates) * 4;
        float a = 0.f;
        for (int k0 = 0; k0 < HH; k0 += KC) {
            #pragma unroll
            for (int rr = 0; rr < BB; rr += 2)
                hT[col][rr + r0] = h_in[(rr + r0) * HH + k0 + col];
            #pragma unroll
            for (int rr = 0; rr < 4; rr += 2)
                wl[rr + r0][col] = fcW[(size_t)(d0 + rr + r0) * HH + k0 + col];
            __syncthreads();
            #pragma unroll 8
            for (int k = 0; k < KC; k += 4) {
                const float4 w0 = *reinterpret_cast<const float4*>(&wl[q][k]);
                const float h0v = hT[k][b], h1v = hT[k + 1][b];
                const float h2v = hT[k + 2][b], h3v = hT[k + 3][b];
                a += h0v * w0.x + h1v * w0.y + h2v * w0.z + h3v * w0.w;
            }
            __syncthreads();
        }
        const int d = d0 + q;
        a += fcb[d];
        if (fc_out)  fc_out[(size_t)b * OUT_BSTRIDE + d] = a;
        if (predbuf) predbuf[b * DXX + d] = a;
    }
}

// -------- prep: biases (enc_b, dec_b, bcomb = dec_b + dec_Wih @ fc_b) --------
__global__ __launch_bounds__(256)
void bias_prep(const float* __restrict__ ebi, const float* __restrict__ ebh,
               const float* __restrict__ dbi, const float* __restrict__ dbh,
               const float* __restrict__ dWih, const float* __restrict__ fcbv,
               float* __restrict__ enc_b, float* __restrict__ dec_b, float* __restrict__ bcomb)
{
    __shared__ float fb[DXX];
    const int t = threadIdx.x;
    const int j = blockIdx.x * 256 + t;
    if (t < DXX) fb[t] = fcbv[t];
    __syncthreads();
    const float eb = ebi[j] + ebh[j];
    const float db = dbi[j] + dbh[j];
    enc_b[j] = eb;
    dec_b[j] = db;
    float acc = db;
    const float* wr = dWih + (size_t)j * DXX;
    for (int d = 0; d < DXX; d += 4) {
        const float4 w = *reinterpret_cast<const float4*>(&wr[d]);
        acc += w.x * fb[d] + w.y * fb[d + 1] + w.z * fb[d + 2] + w.w * fb[d + 3];
    }
    bcomb[j] = acc;
}

// -------- prep: Wcomb[j][n] = dec_Whh[j][n] + sum_d dec_Wih[j][d] * fc_W[d][n] --------
// grid = 2048: (j-group of 8) x (n-group of 256)
__global__ __launch_bounds__(256)
void wcomb_kernel(const float* __restrict__ dWhh, const float* __restrict__ dWih,
                  const float* __restrict__ fcW, float* __restrict__ Wcomb)
{
    const int bi = blockIdx.x;
    const int j0 = (bi >> 2) * 8;
    const int n  = (bi & 3) * 256 + threadIdx.x;
    __shared__ float wih[8][DXX];
    for (int i = threadIdx.x; i < 8 * DXX; i += 256)
        wih[i >> 7][i & 127] = dWih[(size_t)(j0 + (i >> 7)) * DXX + (i & 127)];
    __syncthreads();
    float acc[8];
    #pragma unroll
    for (int jj = 0; jj < 8; ++jj) acc[jj] = dWhh[(size_t)(j0 + jj) * HH + n];
    for (int d = 0; d < DXX; ++d) {
        const float fv = fcW[(size_t)d * HH + n];
        #pragma unroll
        for (int jj = 0; jj < 8; ++jj) acc[jj] += wih[jj][d] * fv;
    }
    #pragma unroll
    for (int jj = 0; jj < 8; ++jj) Wcomb[(size_t)(j0 + jj) * HH + n] = acc[jj];
}

// -------- init: zero h0, c, out[:,0,:] --------
__global__ __launch_bounds__(256)
void init_kernel(float* __restrict__ h0, float* __restrict__ c, float* __restrict__ out)
{
    const int idx = blockIdx.x * 256 + threadIdx.x;
    if (idx < BB * HH) h0[idx] = 0.f;
    else if (idx < 2 * BB * HH) c[idx - BB * HH] = 0.f;
    else {
        const int r = idx - 2 * BB * HH;
        if (r < BB * DXX) out[(size_t)(r >> 7) * OUT_BSTRIDE + (r & 127)] = 0.f;
    }
}

extern "C" void kernel_launch(void* const* d_in, const int* in_sizes, int n_in,
                              void* d_out, int out_size, void* d_ws, size_t ws_size,
                              hipStream_t stream) {
    const float* src   = (const float*)d_in[0];
    const float* trg   = (const float*)d_in[1];
    const float* eWih  = (const float*)d_in[2];
    const float* eWhh  = (const float*)d_in[3];
    const float* ebih  = (const float*)d_in[4];
    const float* ebhh  = (const float*)d_in[5];
    const float* dWih  = (const float*)d_in[6];
    const float* dWhh  = (const float*)d_in[7];
    const float* dbih  = (const float*)d_in[8];
    const float* dbhh  = (const float*)d_in[9];
    const float* fcW   = (const float*)d_in[10];
    const float* fcb   = (const float*)d_in[11];
    float* out = (float*)d_out;
    float* ws  = (float*)d_ws;

    // workspace layout (floats)
    float* h0     = ws;                 // 65536
    float* h1     = ws + 65536;         // 65536
    float* c      = ws + 131072;        // 65536
    float* pred   = ws + 196608;        // 8192
    float* enc_b  = ws + 204800;        // 4096
    float* dec_b  = ws + 208896;        // 4096
    float* bcomb  = ws + 212992;        // 4096
    float* Wcomb  = ws + 217088;        // 4096*1024
    const bool use_comb = ws_size >= (size_t)(217088 + 4096 * 1024) * sizeof(float);

    init_kernel<<<544, 256, 0, stream>>>(h0, c, out);
    bias_prep<<<16, 256, 0, stream>>>(ebih, ebhh, dbih, dbhh, dWih, fcb, enc_b, dec_b, bcomb);
    if (use_comb)
        wcomb_kernel<<<2048, 256, 0, stream>>>(dWhh, dWih, fcW, Wcomb);

    float* hc = h0;
    float* hn = h1;

    // ---- encoder: 256 steps ----
    for (int s = 0; s < SEQN; ++s) {
        step_kernel<<<256, 256, 0, stream>>>(eWhh, eWih, src + s * DXX, SEQN * DXX,
                                             enc_b, hc, c, hn, 256,
                                             nullptr, nullptr, nullptr, nullptr);
        float* tmp = hc; hc = hn; hn = tmp;
    }

    // ---- decoder step 0: input = trg[:,0,:] ----
    step_kernel<<<256, 256, 0, stream>>>(dWhh, dWih, trg, TN * DXX,
                                         dec_b, hc, c, hn, 256,
                                         nullptr, nullptr, nullptr, nullptr);
    { float* tmp = hc; hc = hn; hn = tmp; }

    if (use_comb) {
        // decoder steps 1..254: gates = h @ Wcomb^T + bcomb; fused FC writes out[:,t,:]
        for (int tt = 1; tt <= TN - 2; ++tt) {
            step_kernel<<<288, 256, 0, stream>>>(Wcomb, nullptr, nullptr, 0,
                                                 bcomb, hc, c, hn, 256,
                                                 fcW, fcb, out + (size_t)tt * DXX, nullptr);
            float* tmp = hc; hc = hn; hn = tmp;
        }
    } else {
        // fallback: explicit pred each step
        for (int tt = 1; tt <= TN - 2; ++tt) {
            step_kernel<<<32, 256, 0, stream>>>(nullptr, nullptr, nullptr, 0,
                                                nullptr, hc, nullptr, nullptr, 0,
                                                fcW, fcb, out + (size_t)tt * DXX, pred);
            step_kernel<<<256, 256, 0, stream>>>(dWhh, dWih, pred, DXX,
                                                 dec_b, hc, c, hn, 256,
                                                 nullptr, nullptr, nullptr, nullptr);
            float* tmp = hc; hc = hn; hn = tmp;
        }
    }

    // final FC: out[:,255,:] = fc(h_255)
    step_kernel<<<32, 256, 0, stream>>>(nullptr, nullptr, nullptr, 0,
                                        nullptr, hc, nullptr, nullptr, 0,
                                        fcW, fcb, out + (size_t)(TN - 1) * DXX, nullptr);
}

// Round 2
// 12078.096 us; speedup vs baseline: 1.9013x; 1.9013x over previous
//
#include <hip/hip_runtime.h>

// Seq2Seq LSTM (B=64, S=T=256, DIN=DOUT=128, H=1024).
// Round 2: split-bf16 MFMA step kernels (hi/lo decomposition, 3 MFMA passes,
// fp32 accumulate). One dispatch per recurrence step. Gate-interleaved weight
// layout (row n4 = hid*4+g) so each block's 16/24 columns contain whole
// (i,f,g,o) groups -> fused LSTM cell epilogue. Decoder feedback folded into
// Wcomb = dec_Whh + dec_Wih @ fc_W; FC output folded as extra 128 GEMM rows.
// Round-1 fp32 kernels retained: dec step 0 + full fallback if ws too small.

#define BB   64
#define HH   1024
#define G4   4096
#define DXX  128
#define KC   128
#define SEQN 256
#define TN   256
#define NDEC 4224
#define NDECPAD 5632
#define KENC 1152
#define OUT_BSTRIDE (TN * DXX)

typedef __attribute__((ext_vector_type(8))) short short8;
typedef __attribute__((ext_vector_type(4))) float f32x4;

__device__ __forceinline__ float sigm(float x)  { return 1.f / (1.f + __expf(-x)); }
__device__ __forceinline__ float tanh_f(float x){ return 1.f - 2.f / (1.f + __expf(2.f * x)); }

__device__ __forceinline__ unsigned short bf16_rn(float x) {
    union { float f; unsigned u; } v; v.f = x;
    unsigned r = v.u + 0x7fffu + ((v.u >> 16) & 1u);
    return (unsigned short)(r >> 16);
}
__device__ __forceinline__ float bf16f(unsigned short h) {
    union { unsigned u; float f; } v; v.u = ((unsigned)h) << 16; return v.f;
}

// ---------------- split-bf16 MFMA step kernel ----------------
// grid: N/CPB blocks, 256 threads (4 waves, waves split M=64 into 16-row tiles).
// gates[b][col] = sum_k h[b][k]*W'[col][k] (+ x-part if HASX) + bias[col]
// cols < gateLimit -> LSTM cell (c,h update); cols in [4096,NTOT) -> FC store.
template<int CPB, int KT, bool HASX>
__global__ __launch_bounds__(256)
void mfma_step(const unsigned short* __restrict__ Whi,
               const unsigned short* __restrict__ Wlo, int Kw,
               const unsigned short* __restrict__ hhi,
               const unsigned short* __restrict__ hlo,
               const unsigned short* __restrict__ xhi,
               const unsigned short* __restrict__ xlo, int xstride,
               const float* __restrict__ bias,
               float* __restrict__ c,
               unsigned short* __restrict__ ohhi,
               unsigned short* __restrict__ ohlo,
               float* __restrict__ ohf32,
               float* __restrict__ fc_out,   // out + tt*128 (b-stride 32768)
               int gateLimit, int NTOT)
{
    constexpr int NT = (CPB + 15) / 16;
    const int col0 = blockIdx.x * CPB;
    if (gateLimit == 0 && col0 + CPB <= G4) return;   // final-FC launch: skip gate blocks

    const int l   = threadIdx.x & 63;
    const int wv  = threadIdx.x >> 6;
    const int lm  = l & 15;             // m (A) / n (B) within tile
    const int kl  = (l >> 4) << 3;      // k offset within 32-wide k-tile
    const int mrow = wv * 16 + lm;

    f32x4 acc[NT][3];
    #pragma unroll
    for (int nt = 0; nt < NT; ++nt)
        #pragma unroll
        for (int p = 0; p < 3; ++p) acc[nt][p] = f32x4{0.f, 0.f, 0.f, 0.f};

    const unsigned short* Ah = hhi + mrow * HH + kl;
    const unsigned short* Al = hlo + mrow * HH + kl;
    const unsigned short* Bh = Whi + (size_t)(col0 + lm) * Kw + kl;
    const unsigned short* Bl = Wlo + (size_t)(col0 + lm) * Kw + kl;

    #pragma unroll 4
    for (int kt = 0; kt < KT; ++kt) {
        short8 ah, al;
        if (!HASX || kt < HH / 32) {
            ah = *(const short8*)(Ah + kt * 32);
            al = *(const short8*)(Al + kt * 32);
        } else {
            const int xo = mrow * xstride + (kt - HH / 32) * 32 + kl;
            ah = *(const short8*)(xhi + xo);
            al = *(const short8*)(xlo + xo);
        }
        #pragma unroll
        for (int nt = 0; nt < NT; ++nt) {
            short8 bh = *(const short8*)(Bh + (size_t)nt * 16 * Kw + kt * 32);
            short8 bl = *(const short8*)(Bl + (size_t)nt * 16 * Kw + kt * 32);
            acc[nt][0] = __builtin_amdgcn_mfma_f32_16x16x32_bf16(ah, bh, acc[nt][0], 0, 0, 0);
            acc[nt][1] = __builtin_amdgcn_mfma_f32_16x16x32_bf16(ah, bl, acc[nt][1], 0, 0, 0);
            acc[nt][2] = __builtin_amdgcn_mfma_f32_16x16x32_bf16(al, bh, acc[nt][2], 0, 0, 0);
        }
    }

    __shared__ float g_lds[64][NT * 16 + 1];
    #pragma unroll
    for (int nt = 0; nt < NT; ++nt) {
        f32x4 s = acc[nt][0] + acc[nt][1] + acc[nt][2];
        const float bv = bias[col0 + nt * 16 + lm];
        #pragma unroll
        for (int r = 0; r < 4; ++r)
            g_lds[wv * 16 + (l >> 4) * 4 + r][nt * 16 + lm] = s[r] + bv;
    }
    __syncthreads();

    const int b = threadIdx.x & 63;
    constexpr int ncg = CPB >> 2;
    for (int cg = threadIdx.x >> 6; cg < ncg; cg += 4) {
        const int col = col0 + cg * 4;
        if (col < gateLimit) {
            const float gi = g_lds[b][cg * 4 + 0];
            const float gf = g_lds[b][cg * 4 + 1];
            const float gg = g_lds[b][cg * 4 + 2];
            const float go = g_lds[b][cg * 4 + 3];
            const int ci = b * HH + (col >> 2);
            const float cv = sigm(gf) * c[ci] + sigm(gi) * tanh_f(gg);
            c[ci] = cv;
            const float hv = sigm(go) * tanh_f(cv);
            const unsigned short hh = bf16_rn(hv);
            ohhi[ci] = hh;
            ohlo[ci] = bf16_rn(hv - bf16f(hh));
            if (ohf32) ohf32[ci] = hv;
        } else if (col >= G4 && col < NTOT && fc_out) {
            #pragma unroll
            for (int g = 0; g < 4; ++g)
                fc_out[(size_t)b * OUT_BSTRIDE + (col - G4) + g] = g_lds[b][cg * 4 + g];
        }
    }
}

// ---------------- prep kernels ----------------
__global__ __launch_bounds__(256)
void prep_enc_w(const float* __restrict__ eWhh, const float* __restrict__ eWih,
                unsigned short* __restrict__ Whi, unsigned short* __restrict__ Wlo)
{
    const int n4 = blockIdx.x;                       // 0..4095
    const int orig = ((n4 & 3) << 10) | (n4 >> 2);   // g*1024+hid
    for (int k = threadIdx.x; k < KENC; k += 256) {
        float w = (k < HH) ? eWhh[(size_t)orig * HH + k]
                           : eWih[(size_t)orig * DXX + (k - HH)];
        unsigned short hi = bf16_rn(w);
        Whi[(size_t)n4 * KENC + k] = hi;
        Wlo[(size_t)n4 * KENC + k] = bf16_rn(w - bf16f(hi));
    }
}

__global__ __launch_bounds__(256)
void prep_dec_w(const float* __restrict__ dWhh, const float* __restrict__ dWih,
                const float* __restrict__ fcW,
                unsigned short* __restrict__ Whi, unsigned short* __restrict__ Wlo)
{
    const int bi = blockIdx.x;             // 2048: j-group 8 x n-chunk 256
    const int j0 = (bi >> 2) * 8;
    const int n  = (bi & 3) * 256 + threadIdx.x;
    __shared__ float wih[8][DXX];
    for (int i = threadIdx.x; i < 8 * DXX; i += 256)
        wih[i >> 7][i & 127] = dWih[(size_t)(j0 + (i >> 7)) * DXX + (i & 127)];
    __syncthreads();
    float acc[8];
    #pragma unroll
    for (int jj = 0; jj < 8; ++jj) acc[jj] = dWhh[(size_t)(j0 + jj) * HH + n];
    for (int d = 0; d < DXX; ++d) {
        const float fv = fcW[(size_t)d * HH + n];
        #pragma unroll
        for (int jj = 0; jj < 8; ++jj) acc[jj] += wih[jj][d] * fv;
    }
    #pragma unroll
    for (int jj = 0; jj < 8; ++jj) {
        const int j = j0 + jj;
        const int row4 = ((j & (HH - 1)) << 2) | (j >> 10);
        unsigned short hi = bf16_rn(acc[jj]);
        Whi[(size_t)row4 * HH + n] = hi;
        Wlo[(size_t)row4 * HH + n] = bf16_rn(acc[jj] - bf16f(hi));
    }
}

__global__ __launch_bounds__(256)
void prep_dec_fc_w(const float* __restrict__ fcW,
                   unsigned short* __restrict__ Whi, unsigned short* __restrict__ Wlo)
{
    const int d = blockIdx.x;   // 0..127
    for (int k = threadIdx.x; k < HH; k += 256) {
        float w = fcW[(size_t)d * HH + k];
        unsigned short hi = bf16_rn(w);
        Whi[(size_t)(G4 + d) * HH + k] = hi;
        Wlo[(size_t)(G4 + d) * HH + k] = bf16_rn(w - bf16f(hi));
    }
}

__global__ __launch_bounds__(256)
void prep_bias(const float* __restrict__ ebi, const float* __restrict__ ebh,
               const float* __restrict__ dbi, const float* __restrict__ dbh,
               const float* __restrict__ dWih, const float* __restrict__ fcb,
               float* __restrict__ benc, float* __restrict__ bdec,
               float* __restrict__ dec_b_orig)
{
    const int idx = blockIdx.x * 256 + threadIdx.x;   // grid 22 -> 5632
    if (idx < G4) {
        const int orig = ((idx & 3) << 10) | (idx >> 2);
        benc[idx] = ebi[orig] + ebh[orig];
        float a = dbi[orig] + dbh[orig];
        const float* wr = dWih + (size_t)orig * DXX;
        for (int d = 0; d < DXX; ++d) a += wr[d] * fcb[d];
        bdec[idx] = a;
        dec_b_orig[idx] = dbi[idx] + dbh[idx];
    } else if (idx < NDEC) {
        bdec[idx] = fcb[idx - G4];
    } else if (idx < NDECPAD) {
        bdec[idx] = 0.f;
    }
}

__global__ __launch_bounds__(256)
void prep_src(const float* __restrict__ src, unsigned short* __restrict__ shi,
              unsigned short* __restrict__ slo, int n)
{
    const int idx = blockIdx.x * 256 + threadIdx.x;
    if (idx < n) {
        float v = src[idx];
        unsigned short hi = bf16_rn(v);
        shi[idx] = hi;
        slo[idx] = bf16_rn(v - bf16f(hi));
    }
}

__global__ __launch_bounds__(256)
void init_fast(float* __restrict__ c, unsigned short* __restrict__ hhi,
               unsigned short* __restrict__ hlo, float* __restrict__ out)
{
    const int idx = blockIdx.x * 256 + threadIdx.x;   // grid 288
    if (idx < BB * HH) { c[idx] = 0.f; hhi[idx] = 0; hlo[idx] = 0; }
    else {
        const int r = idx - BB * HH;
        if (r < BB * DXX) out[(size_t)(r >> 7) * OUT_BSTRIDE + (r & 127)] = 0.f;
    }
}

// ---------------- round-1 fp32 kernels (dec step 0 + fallback) ----------------
__global__ __launch_bounds__(256)
void step_kernel(const float* __restrict__ W, const float* __restrict__ Wx,
                 const float* __restrict__ x, int xstride,
                 const float* __restrict__ bias,
                 const float* __restrict__ h_in, float* __restrict__ c,
                 float* __restrict__ h_out, int nGates,
                 const float* __restrict__ fcW, const float* __restrict__ fcb,
                 float* __restrict__ fc_out, float* __restrict__ predbuf,
                 unsigned short* __restrict__ ohhi, unsigned short* __restrict__ ohlo)
{
    __shared__ float hT[KC][BB + 1];
    __shared__ float wl[16][KC];

    const int t   = threadIdx.x;
    const int b   = t & 63;
    const int q   = t >> 6;
    const int col = t & (KC - 1);
    const int r0  = t >> 7;
    const int bi  = blockIdx.x;

    if (bi < nGates) {
        const int n0 = bi * 4;
        const int n  = n0 + q;
        float a0 = bias[n];
        float a1 = bias[HH + n];
        float a2 = bias[2 * HH + n];
        float a3 = bias[3 * HH + n];

        for (int k0 = 0; k0 < HH; k0 += KC) {
            #pragma unroll
            for (int rr = 0; rr < BB; rr += 2)
                hT[col][rr + r0] = h_in[(rr + r0) * HH + k0 + col];
            #pragma unroll
            for (int rr = 0; rr < 16; rr += 2) {
                const int r = rr + r0;
                const int j = (r & 3) * HH + n0 + (r >> 2);
                wl[r][col] = W[(size_t)j * HH + k0 + col];
            }
            __syncthreads();
            #pragma unroll 8
            for (int k = 0; k < KC; k += 4) {
                const float4 w0 = *reinterpret_cast<const float4*>(&wl[q * 4 + 0][k]);
                const float4 w1 = *reinterpret_cast<const float4*>(&wl[q * 4 + 1][k]);
                const float4 w2 = *reinterpret_cast<const float4*>(&wl[q * 4 + 2][k]);
                const float4 w3 = *reinterpret_cast<const float4*>(&wl[q * 4 + 3][k]);
                const float h0v = hT[k][b], h1v = hT[k + 1][b];
                const float h2v = hT[k + 2][b], h3v = hT[k + 3][b];
                a0 += h0v * w0.x + h1v * w0.y + h2v * w0.z + h3v * w0.w;
                a1 += h0v * w1.x + h1v * w1.y + h2v * w1.z + h3v * w1.w;
                a2 += h0v * w2.x + h1v * w2.y + h2v * w2.z + h3v * w2.w;
                a3 += h0v * w3.x + h1v * w3.y + h2v * w3.z + h3v * w3.w;
            }
            __syncthreads();
        }

        if (Wx != nullptr) {
            #pragma unroll
            for (int rr = 0; rr < BB; rr += 2)
                hT[col][rr + r0] = x[(size_t)(rr + r0) * xstride + col];
            #pragma unroll
            for (int rr = 0; rr < 16; rr += 2) {
                const int r = rr + r0;
                const int j = (r & 3) * HH + n0 + (r >> 2);
                wl[r][col] = Wx[(size_t)j * DXX + col];
            }
            __syncthreads();
            #pragma unroll 8
            for (int k = 0; k < DXX; k += 4) {
                const float4 w0 = *reinterpret_cast<const float4*>(&wl[q * 4 + 0][k]);
                const float4 w1 = *reinterpret_cast<const float4*>(&wl[q * 4 + 1][k]);
                const float4 w2 = *reinterpret_cast<const float4*>(&wl[q * 4 + 2][k]);
                const float4 w3 = *reinterpret_cast<const float4*>(&wl[q * 4 + 3][k]);
                const float h0v = hT[k][b], h1v = hT[k + 1][b];
                const float h2v = hT[k + 2][b], h3v = hT[k + 3][b];
                a0 += h0v * w0.x + h1v * w0.y + h2v * w0.z + h3v * w0.w;
                a1 += h0v * w1.x + h1v * w1.y + h2v * w1.z + h3v * w1.w;
                a2 += h0v * w2.x + h1v * w2.y + h2v * w2.z + h3v * w2.w;
                a3 += h0v * w3.x + h1v * w3.y + h2v * w3.z + h3v * w3.w;
            }
        }

        const int ci = b * HH + n;
        const float iv = sigm(a0);
        const float fv = sigm(a1);
        const float gv = tanh_f(a2);
        const float ov = sigm(a3);
        const float cv = fv * c[ci] + iv * gv;
        c[ci]     = cv;
        const float hv = ov * tanh_f(cv);
        h_out[ci] = hv;
        if (ohhi) {
            const unsigned short hh = bf16_rn(hv);
            ohhi[ci] = hh;
            ohlo[ci] = bf16_rn(hv - bf16f(hh));
        }
    } else if (fcW != nullptr && bi < nGates + 32) {
        const int d0 = (bi - nGates) * 4;
        float a = 0.f;
        for (int k0 = 0; k0 < HH; k0 += KC) {
            #pragma unroll
            for (int rr = 0; rr < BB; rr += 2)
                hT[col][rr + r0] = h_in[(rr + r0) * HH + k0 + col];
            #pragma unroll
            for (int rr = 0; rr < 4; rr += 2)
                wl[rr + r0][col] = fcW[(size_t)(d0 + rr + r0) * HH + k0 + col];
            __syncthreads();
            #pragma unroll 8
            for (int k = 0; k < KC; k += 4) {
                const float4 w0 = *reinterpret_cast<const float4*>(&wl[q][k]);
                const float h0v = hT[k][b], h1v = hT[k + 1][b];
                const float h2v = hT[k + 2][b], h3v = hT[k + 3][b];
                a += h0v * w0.x + h1v * w0.y + h2v * w0.z + h3v * w0.w;
            }
            __syncthreads();
        }
        const int d = d0 + q;
        a += fcb[d];
        if (fc_out)  fc_out[(size_t)b * OUT_BSTRIDE + d] = a;
        if (predbuf) predbuf[b * DXX + d] = a;
    }
}

__global__ __launch_bounds__(256)
void bias_prep(const float* __restrict__ ebi, const float* __restrict__ ebh,
               const float* __restrict__ dbi, const float* __restrict__ dbh,
               const float* __restrict__ dWih, const float* __restrict__ fcbv,
               float* __restrict__ enc_b, float* __restrict__ dec_b, float* __restrict__ bcomb)
{
    __shared__ float fb[DXX];
    const int t = threadIdx.x;
    const int j = blockIdx.x * 256 + t;
    if (t < DXX) fb[t] = fcbv[t];
    __syncthreads();
    const float eb = ebi[j] + ebh[j];
    const float db = dbi[j] + dbh[j];
    enc_b[j] = eb;
    dec_b[j] = db;
    float acc = db;
    const float* wr = dWih + (size_t)j * DXX;
    for (int d = 0; d < DXX; d += 4) {
        const float4 w = *reinterpret_cast<const float4*>(&wr[d]);
        acc += w.x * fb[d] + w.y * fb[d + 1] + w.z * fb[d + 2] + w.w * fb[d + 3];
    }
    bcomb[j] = acc;
}

__global__ __launch_bounds__(256)
void wcomb_kernel(const float* __restrict__ dWhh, const float* __restrict__ dWih,
                  const float* __restrict__ fcW, float* __restrict__ Wcomb)
{
    const int bi = blockIdx.x;
    const int j0 = (bi >> 2) * 8;
    const int n  = (bi & 3) * 256 + threadIdx.x;
    __shared__ float wih[8][DXX];
    for (int i = threadIdx.x; i < 8 * DXX; i += 256)
        wih[i >> 7][i & 127] = dWih[(size_t)(j0 + (i >> 7)) * DXX + (i & 127)];
    __syncthreads();
    float acc[8];
    #pragma unroll
    for (int jj = 0; jj < 8; ++jj) acc[jj] = dWhh[(size_t)(j0 + jj) * HH + n];
    for (int d = 0; d < DXX; ++d) {
        const float fv = fcW[(size_t)d * HH + n];
        #pragma unroll
        for (int jj = 0; jj < 8; ++jj) acc[jj] += wih[jj][d] * fv;
    }
    #pragma unroll
    for (int jj = 0; jj < 8; ++jj) Wcomb[(size_t)(j0 + jj) * HH + n] = acc[jj];
}

__global__ __launch_bounds__(256)
void init_kernel(float* __restrict__ h0, float* __restrict__ c, float* __restrict__ out)
{
    const int idx = blockIdx.x * 256 + threadIdx.x;
    if (idx < BB * HH) h0[idx] = 0.f;
    else if (idx < 2 * BB * HH) c[idx - BB * HH] = 0.f;
    else {
        const int r = idx - 2 * BB * HH;
        if (r < BB * DXX) out[(size_t)(r >> 7) * OUT_BSTRIDE + (r & 127)] = 0.f;
    }
}

// ---------------- host ----------------
extern "C" void kernel_launch(void* const* d_in, const int* in_sizes, int n_in,
                              void* d_out, int out_size, void* d_ws, size_t ws_size,
                              hipStream_t stream) {
    const float* src   = (const float*)d_in[0];
    const float* trg   = (const float*)d_in[1];
    const float* eWih  = (const float*)d_in[2];
    const float* eWhh  = (const float*)d_in[3];
    const float* ebih  = (const float*)d_in[4];
    const float* ebhh  = (const float*)d_in[5];
    const float* dWih  = (const float*)d_in[6];
    const float* dWhh  = (const float*)d_in[7];
    const float* dbih  = (const float*)d_in[8];
    const float* dbhh  = (const float*)d_in[9];
    const float* fcW   = (const float*)d_in[10];
    const float* fcb   = (const float*)d_in[11];
    float* out = (float*)d_out;

    // ---- fast-path workspace layout ----
    uintptr_t base = (uintptr_t)d_ws;
    size_t off = 0;
    auto alloc = [&](size_t bytes) -> void* {
        void* p = (void*)(base + off);
        off = (off + bytes + 255) & ~(size_t)255;
        return p;
    };
    unsigned short* Hhi[2], *Hlo[2];
    Hhi[0] = (unsigned short*)alloc(BB * HH * 2);
    Hlo[0] = (unsigned short*)alloc(BB * HH * 2);
    Hhi[1] = (unsigned short*)alloc(BB * HH * 2);
    Hlo[1] = (unsigned short*)alloc(BB * HH * 2);
    float* hf32A = (float*)alloc(BB * HH * 4);
    float* hf32B = (float*)alloc(BB * HH * 4);
    float* c     = (float*)alloc(BB * HH * 4);
    float* benc  = (float*)alloc(G4 * 4);
    float* bdec  = (float*)alloc(NDECPAD * 4);
    float* dec_b_orig = (float*)alloc(G4 * 4);
    unsigned short* Wenchi = (unsigned short*)alloc((size_t)G4 * KENC * 2);
    unsigned short* Wenclo = (unsigned short*)alloc((size_t)G4 * KENC * 2);
    unsigned short* Wdechi = (unsigned short*)alloc((size_t)NDECPAD * HH * 2);
    unsigned short* Wdeclo = (unsigned short*)alloc((size_t)NDECPAD * HH * 2);
    unsigned short* srchi  = (unsigned short*)alloc((size_t)BB * SEQN * DXX * 2);
    unsigned short* srclo  = (unsigned short*)alloc((size_t)BB * SEQN * DXX * 2);
    const bool fast = (off <= ws_size);

    if (fast) {
        init_fast<<<288, 256, 0, stream>>>(c, Hhi[0], Hlo[0], out);
        prep_enc_w<<<G4, 256, 0, stream>>>(eWhh, eWih, Wenchi, Wenclo);
        prep_dec_w<<<2048, 256, 0, stream>>>(dWhh, dWih, fcW, Wdechi, Wdeclo);
        prep_dec_fc_w<<<DXX, 256, 0, stream>>>(fcW, Wdechi, Wdeclo);
        prep_bias<<<22, 256, 0, stream>>>(ebih, ebhh, dbih, dbhh, dWih, fcb,
                                          benc, bdec, dec_b_orig);
        prep_src<<<8192, 256, 0, stream>>>(src, srchi, srclo, BB * SEQN * DXX);

        int cur = 0;
        // encoder: 256 steps (K = 1024 h + 128 x)
        for (int s = 0; s < SEQN; ++s) {
            mfma_step<16, 36, true><<<256, 256, 0, stream>>>(
                Wenchi, Wenclo, KENC,
                Hhi[cur], Hlo[cur], srchi + s * DXX, srclo + s * DXX, SEQN * DXX,
                benc, c, Hhi[cur ^ 1], Hlo[cur ^ 1],
                (s == SEQN - 1) ? hf32A : nullptr,
                nullptr, G4, G4);
            cur ^= 1;
        }
        // decoder step 0 (input = trg[:,0,:]) via fp32 round-1 kernel
        step_kernel<<<256, 256, 0, stream>>>(dWhh, dWih, trg, TN * DXX, dec_b_orig,
                                             hf32A, c, hf32B, 256,
                                             nullptr, nullptr, nullptr, nullptr,
                                             Hhi[cur ^ 1], Hlo[cur ^ 1]);
        cur ^= 1;
        // decoder steps 1..254: Wcomb GEMM + fused FC -> out[:,tt,:]
        for (int tt = 1; tt <= TN - 2; ++tt) {
            mfma_step<24, 32, false><<<176, 256, 0, stream>>>(
                Wdechi, Wdeclo, HH,
                Hhi[cur], Hlo[cur], nullptr, nullptr, 0,
                bdec, c, Hhi[cur ^ 1], Hlo[cur ^ 1], nullptr,
                out + (size_t)tt * DXX, G4, NDEC);
            cur ^= 1;
        }
        // final FC: out[:,255,:] = fc(h_255) (gateLimit=0 -> FC blocks only)
        mfma_step<24, 32, false><<<176, 256, 0, stream>>>(
            Wdechi, Wdeclo, HH,
            Hhi[cur], Hlo[cur], nullptr, nullptr, 0,
            bdec, c, Hhi[cur ^ 1], Hlo[cur ^ 1], nullptr,
            out + (size_t)(TN - 1) * DXX, 0, NDEC);
        return;
    }

    // ---- fallback: round-1 fp32 path ----
    float* ws  = (float*)d_ws;
    float* h0     = ws;
    float* h1     = ws + 65536;
    float* cF     = ws + 131072;
    float* pred   = ws + 196608;
    float* enc_b  = ws + 204800;
    float* dec_b  = ws + 208896;
    float* bcomb  = ws + 212992;
    float* Wcomb  = ws + 217088;
    const bool use_comb = ws_size >= (size_t)(217088 + 4096 * 1024) * sizeof(float);

    init_kernel<<<544, 256, 0, stream>>>(h0, cF, out);
    bias_prep<<<16, 256, 0, stream>>>(ebih, ebhh, dbih, dbhh, dWih, fcb, enc_b, dec_b, bcomb);
    if (use_comb)
        wcomb_kernel<<<2048, 256, 0, stream>>>(dWhh, dWih, fcW, Wcomb);

    float* hc = h0;
    float* hn = h1;
    for (int s = 0; s < SEQN; ++s) {
        step_kernel<<<256, 256, 0, stream>>>(eWhh, eWih, src + s * DXX, SEQN * DXX,
                                             enc_b, hc, cF, hn, 256,
                                             nullptr, nullptr, nullptr, nullptr,
                                             nullptr, nullptr);
        float* tmp = hc; hc = hn; hn = tmp;
    }
    step_kernel<<<256, 256, 0, stream>>>(dWhh, dWih, trg, TN * DXX,
                                         dec_b, hc, cF, hn, 256,
                                         nullptr, nullptr, nullptr, nullptr,
                                         nullptr, nullptr);
    { float* tmp = hc; hc = hn; hn = tmp; }

    if (use_comb) {
        for (int tt = 1; tt <= TN - 2; ++tt) {
            step_kernel<<<288, 256, 0, stream>>>(Wcomb, nullptr, nullptr, 0,
                                                 bcomb, hc, cF, hn, 256,
                                                 fcW, fcb, out + (size_t)tt * DXX, nullptr,
                                                 nullptr, nullptr);
            float* tmp = hc; hc = hn; hn = tmp;
        }
    } else {
        for (int tt = 1; tt <= TN - 2; ++tt) {
            step_kernel<<<32, 256, 0, stream>>>(nullptr, nullptr, nullptr, 0,
                                                nullptr, hc, nullptr, nullptr, 0,
                                                fcW, fcb, out + (size_t)tt * DXX, pred,
                                                nullptr, nullptr);
            step_kernel<<<256, 256, 0, stream>>>(dWhh, dWih, pred, DXX,
                                                 dec_b, hc, cF, hn, 256,
                                                 nullptr, nullptr, nullptr, nullptr,
                                                 nullptr, nullptr);
            float* tmp = hc; hc = hn; hn = tmp;
        }
    }
    step_kernel<<<32, 256, 0, stream>>>(nullptr, nullptr, nullptr, 0,
                                        nullptr, hc, nullptr, nullptr, 0,
                                        fcW, fcb, out + (size_t)(TN - 1) * DXX, nullptr,
                                        nullptr, nullptr);
}

// Round 3
// 6305.640 us; speedup vs baseline: 3.6419x; 1.9154x over previous
//
#include <hip/hip_runtime.h>

// Seq2Seq LSTM (B=64, S=T=256, DIN=DOUT=128, H=1024).
// Round 3: 1024-thread (16-wave) split-bf16 MFMA step kernels.
//  - B (weights) LDS-resident per block, staged once from block-tiled layout,
//    XOR-swizzled for conflict-free ds_read_b128.
//  - A (h state, hi|lo combined [64][2048]) direct from global (L2).
//  - 16 waves = (4 m-tiles) x (4 k-quarters), no barriers in main loop,
//    LDS reduction + fused LSTM-cell / FC epilogue.
//  - Decoder: 256 gate tiles + 8 fat blocks carrying the 128 FC cols (NT=2).
// Decoder feedback folded into Wcomb = dec_Whh + dec_Wih @ fc_W (as r1/r2).

#define BB   64
#define HH   1024
#define G4   4096
#define DXX  128
#define KC   128
#define SEQN 256
#define TN   256
#define OUT_BSTRIDE (TN * DXX)

#define ENC_COL_H   2320          // halves per col (hi 0..1151, lo 1160..2311)
#define ENC_TILE_H  (16 * 2320)   // 37120 halves per block tile
#define ENC_COL_B   4640
#define DEC_COL_H   2064          // hi 0..1023, lo 1032..2055
#define DEC_TILE_H  (16 * 2064)   // 33024
#define DEC_COL_B   4128

#define ENC_LDS_RED 74240
#define ENC_LDS_SZ  (74240 + 4 * 64 * 17 * 4)        // 91648
#define DEC_LDS_B1  66048
#define DEC_LDS_RED 132096
#define DEC_LDS_SZ  (132096 + 4 * 64 * 17 * 4)       // 149504

typedef __attribute__((ext_vector_type(8))) short short8;
typedef __attribute__((ext_vector_type(4))) float f32x4;

__device__ __forceinline__ float sigm(float x)  { return 1.f / (1.f + __expf(-x)); }
__device__ __forceinline__ float tanh_f(float x){ return 1.f - 2.f / (1.f + __expf(2.f * x)); }

__device__ __forceinline__ unsigned short bf16_rn(float x) {
    union { float f; unsigned u; } v; v.f = x;
    unsigned r = v.u + 0x7fffu + ((v.u >> 16) & 1u);
    return (unsigned short)(r >> 16);
}
__device__ __forceinline__ float bf16f(unsigned short h) {
    union { unsigned u; float f; } v; v.u = ((unsigned)h) << 16; return v.f;
}

// ---------------- encoder step (K = 1024 h + 128 x) ----------------
__global__ __launch_bounds__(1024)
void enc_step(const unsigned short* __restrict__ Wt,   // [256][37120] block-tiled
              const unsigned short* __restrict__ h,    // [64][2048] hi|lo
              const unsigned short* __restrict__ xs,   // [64][256] this step hi|lo
              const float* __restrict__ bias,          // [4096] interleaved
              float* __restrict__ c,
              unsigned short* __restrict__ ho,         // [64][2048]
              float* __restrict__ hof32)               // null or [64][1024]
{
    extern __shared__ unsigned char lds[];
    float* red = (float*)(lds + ENC_LDS_RED);

    const int t  = threadIdx.x;
    const int bi = blockIdx.x;

    {   // stage B tile: 4640 x 16B units, swizzled
        const unsigned short* g = Wt + (size_t)bi * ENC_TILE_H;
        #pragma unroll
        for (int it = 0; it < 5; ++it) {
            const int u = it * 1024 + t;
            if (u < 4640) {
                const int cc  = u / 290;
                const int off = u - cc * 290;
                const short8 v = *(const short8*)(g + u * 8);
                *(short8*)(lds + ((cc * ENC_COL_B + off * 16) ^ ((cc & 7) << 4))) = v;
            }
        }
    }
    __syncthreads();

    const int l    = t & 63;
    const int wv   = t >> 6;
    const int mw   = wv & 3;
    const int kw   = wv >> 2;
    const int lm   = l & 15;
    const int kl   = (l >> 4) << 3;
    const int mrow = mw * 16 + lm;
    const int cswz = (lm & 7) << 4;
    const int bb0  = lm * ENC_COL_B;

    f32x4 a0 = {0.f,0.f,0.f,0.f}, a1 = {0.f,0.f,0.f,0.f}, a2 = {0.f,0.f,0.f,0.f};

    #pragma unroll
    for (int kt = 0; kt < 9; ++kt) {
        const int kg = kw * 288 + kt * 32 + kl;
        short8 ah, al;
        if (kw == 3 && kt >= 5) {
            const int xo = mrow * 256 + (kg - 1024);
            ah = *(const short8*)(xs + xo);
            al = *(const short8*)(xs + xo + 128);
        } else {
            ah = *(const short8*)(h + mrow * 2048 + kg);
            al = *(const short8*)(h + mrow * 2048 + 1024 + kg);
        }
        const short8 bh = *(const short8*)(lds + ((bb0 + 2 * kg) ^ cswz));
        const short8 bl = *(const short8*)(lds + ((bb0 + 2320 + 2 * kg) ^ cswz));
        a0 = __builtin_amdgcn_mfma_f32_16x16x32_bf16(ah, bh, a0, 0, 0, 0);
        a1 = __builtin_amdgcn_mfma_f32_16x16x32_bf16(ah, bl, a1, 0, 0, 0);
        a2 = __builtin_amdgcn_mfma_f32_16x16x32_bf16(al, bh, a2, 0, 0, 0);
    }

    {
        const f32x4 s = a0 + a1 + a2;
        const int rrow = mw * 16 + (l >> 4) * 4;
        #pragma unroll
        for (int r = 0; r < 4; ++r)
            red[(kw * 64 + rrow + r) * 17 + lm] = s[r];
    }
    __syncthreads();

    if (t < 256) {
        const int b  = t >> 2;
        const int nl = t & 3;
        float g4[4];
        #pragma unroll
        for (int gt = 0; gt < 4; ++gt) {
            const int cc = nl * 4 + gt;
            g4[gt] = red[(b) * 17 + cc] + red[(64 + b) * 17 + cc]
                   + red[(128 + b) * 17 + cc] + red[(192 + b) * 17 + cc]
                   + bias[bi * 16 + cc];
        }
        const int nh = bi * 4 + nl;
        const int ci = b * HH + nh;
        const float cv = sigm(g4[1]) * c[ci] + sigm(g4[0]) * tanh_f(g4[2]);
        c[ci] = cv;
        const float hv = sigm(g4[3]) * tanh_f(cv);
        const unsigned short hh = bf16_rn(hv);
        ho[b * 2048 + nh] = hh;
        ho[b * 2048 + 1024 + nh] = bf16_rn(hv - bf16f(hh));
        if (hof32) hof32[b * HH + nh] = hv;
    }
}

// ---------------- decoder step (Wcomb, K = 1024; fat blocks add FC tile) ----------------
__global__ __launch_bounds__(1024)
void dec_step(const unsigned short* __restrict__ Wt,   // [264][33024] block-tiled
              const unsigned short* __restrict__ h,    // [64][2048]
              const float* __restrict__ bias,          // [4224]
              float* __restrict__ c,
              unsigned short* __restrict__ ho,
              float* __restrict__ out_t,               // out + tt*128
              int fcOnly)
{
    extern __shared__ unsigned char lds[];
    unsigned char* B1 = lds + DEC_LDS_B1;
    float* red = (float*)(lds + DEC_LDS_RED);

    const int t  = threadIdx.x;
    const int bi = blockIdx.x;
    const bool fat = (bi & 31) == 0;
    if (fcOnly && !fat) return;
    const int f = bi >> 5;

    if (!fcOnly) {
        const unsigned short* g = Wt + (size_t)bi * DEC_TILE_H;
        #pragma unroll
        for (int it = 0; it < 5; ++it) {
            const int u = it * 1024 + t;
            if (u < 4128) {
                const int cc  = u / 258;
                const int off = u - cc * 258;
                const short8 v = *(const short8*)(g + u * 8);
                *(short8*)(lds + ((cc * DEC_COL_B + off * 16) ^ ((cc & 7) << 4))) = v;
            }
        }
    }
    if (fat) {
        const unsigned short* g = Wt + (size_t)(256 + f) * DEC_TILE_H;
        #pragma unroll
        for (int it = 0; it < 5; ++it) {
            const int u = it * 1024 + t;
            if (u < 4128) {
                const int cc  = u / 258;
                const int off = u - cc * 258;
                const short8 v = *(const short8*)(g + u * 8);
                *(short8*)(B1 + ((cc * DEC_COL_B + off * 16) ^ ((cc & 7) << 4))) = v;
            }
        }
    }
    __syncthreads();

    const int l    = t & 63;
    const int wv   = t >> 6;
    const int mw   = wv & 3;
    const int kw   = wv >> 2;
    const int lm   = l & 15;
    const int kl   = (l >> 4) << 3;
    const int mrow = mw * 16 + lm;
    const int cswz = (lm & 7) << 4;
    const int bb0  = lm * DEC_COL_B;

    f32x4 a0 = {0.f,0.f,0.f,0.f}, a1 = {0.f,0.f,0.f,0.f}, a2 = {0.f,0.f,0.f,0.f};
    f32x4 d0 = {0.f,0.f,0.f,0.f}, d1 = {0.f,0.f,0.f,0.f}, d2 = {0.f,0.f,0.f,0.f};

    #pragma unroll
    for (int kt = 0; kt < 8; ++kt) {
        const int kg = kw * 256 + kt * 32 + kl;
        const short8 ah = *(const short8*)(h + mrow * 2048 + kg);
        const short8 al = *(const short8*)(h + mrow * 2048 + 1024 + kg);
        if (!fcOnly) {
            const short8 bh = *(const short8*)(lds + ((bb0 + 2 * kg) ^ cswz));
            const short8 bl = *(const short8*)(lds + ((bb0 + 2064 + 2 * kg) ^ cswz));
            a0 = __builtin_amdgcn_mfma_f32_16x16x32_bf16(ah, bh, a0, 0, 0, 0);
            a1 = __builtin_amdgcn_mfma_f32_16x16x32_bf16(ah, bl, a1, 0, 0, 0);
            a2 = __builtin_amdgcn_mfma_f32_16x16x32_bf16(al, bh, a2, 0, 0, 0);
        }
        if (fat) {
            const short8 bh = *(const short8*)(B1 + ((bb0 + 2 * kg) ^ cswz));
            const short8 bl = *(const short8*)(B1 + ((bb0 + 2064 + 2 * kg) ^ cswz));
            d0 = __builtin_amdgcn_mfma_f32_16x16x32_bf16(ah, bh, d0, 0, 0, 0);
            d1 = __builtin_amdgcn_mfma_f32_16x16x32_bf16(ah, bl, d1, 0, 0, 0);
            d2 = __builtin_amdgcn_mfma_f32_16x16x32_bf16(al, bh, d2, 0, 0, 0);
        }
    }

    const int rrow = mw * 16 + (l >> 4) * 4;

    if (!fcOnly) {
        const f32x4 s = a0 + a1 + a2;
        #pragma unroll
        for (int r = 0; r < 4; ++r)
            red[(kw * 64 + rrow + r) * 17 + lm] = s[r];
        __syncthreads();
        if (t < 256) {
            const int b  = t >> 2;
            const int nl = t & 3;
            float g4[4];
            #pragma unroll
            for (int gt = 0; gt < 4; ++gt) {
                const int cc = nl * 4 + gt;
                g4[gt] = red[(b) * 17 + cc] + red[(64 + b) * 17 + cc]
                       + red[(128 + b) * 17 + cc] + red[(192 + b) * 17 + cc]
                       + bias[bi * 16 + cc];
            }
            const int nh = bi * 4 + nl;
            const int ci = b * HH + nh;
            const float cv = sigm(g4[1]) * c[ci] + sigm(g4[0]) * tanh_f(g4[2]);
            c[ci] = cv;
            const float hv = sigm(g4[3]) * tanh_f(cv);
            const unsigned short hh = bf16_rn(hv);
            ho[b * 2048 + nh] = hh;
            ho[b * 2048 + 1024 + nh] = bf16_rn(hv - bf16f(hh));
        }
    }
    if (fat) {
        __syncthreads();   // epilogue reads of red done before overwrite
        const f32x4 s = d0 + d1 + d2;
        #pragma unroll
        for (int r = 0; r < 4; ++r)
            red[(kw * 64 + rrow + r) * 17 + lm] = s[r];
        __syncthreads();
        if (t < 256) {
            const int b  = t >> 2;
            const int nl = t & 3;
            #pragma unroll
            for (int gt = 0; gt < 4; ++gt) {
                const int cc = nl * 4 + gt;
                const float v = red[(b) * 17 + cc] + red[(64 + b) * 17 + cc]
                              + red[(128 + b) * 17 + cc] + red[(192 + b) * 17 + cc]
                              + bias[G4 + f * 16 + cc];
                out_t[(size_t)b * OUT_BSTRIDE + f * 16 + cc] = v;
            }
        }
    }
}

// ---------------- prep kernels ----------------
__global__ __launch_bounds__(256)
void prep_enc_w(const float* __restrict__ eWhh, const float* __restrict__ eWih,
                unsigned short* __restrict__ Wt)
{
    const int n4 = blockIdx.x;                       // 0..4095 interleaved col
    const int orig = ((n4 & 3) << 10) | (n4 >> 2);   // g*1024+hid
    const int bi = n4 >> 4, cc = n4 & 15;
    unsigned short* dst = Wt + (size_t)bi * ENC_TILE_H + cc * ENC_COL_H;
    for (int k = threadIdx.x; k < 1152; k += 256) {
        const float w = (k < HH) ? eWhh[(size_t)orig * HH + k]
                                 : eWih[(size_t)orig * DXX + (k - HH)];
        const unsigned short hi = bf16_rn(w);
        dst[k] = hi;
        dst[1160 + k] = bf16_rn(w - bf16f(hi));
    }
}

__global__ __launch_bounds__(256)
void prep_dec_w(const float* __restrict__ dWhh, const float* __restrict__ dWih,
                const float* __restrict__ fcW, unsigned short* __restrict__ Wt)
{
    const int bi = blockIdx.x;             // 2048: j-group 8 x n-chunk 256
    const int j0 = (bi >> 2) * 8;
    const int n  = (bi & 3) * 256 + threadIdx.x;
    __shared__ float wih[8][DXX];
    for (int i = threadIdx.x; i < 8 * DXX; i += 256)
        wih[i >> 7][i & 127] = dWih[(size_t)(j0 + (i >> 7)) * DXX + (i & 127)];
    __syncthreads();
    float acc[8];
    #pragma unroll
    for (int jj = 0; jj < 8; ++jj) acc[jj] = dWhh[(size_t)(j0 + jj) * HH + n];
    for (int d = 0; d < DXX; ++d) {
        const float fv = fcW[(size_t)d * HH + n];
        #pragma unroll
        for (int jj = 0; jj < 8; ++jj) acc[jj] += wih[jj][d] * fv;
    }
    #pragma unroll
    for (int jj = 0; jj < 8; ++jj) {
        const int j = j0 + jj;
        const int row4 = ((j & (HH - 1)) << 2) | (j >> 10);
        const int tb = row4 >> 4, cc = row4 & 15;
        unsigned short* dst = Wt + (size_t)tb * DEC_TILE_H + cc * DEC_COL_H;
        const unsigned short hi = bf16_rn(acc[jj]);
        dst[n] = hi;
        dst[1032 + n] = bf16_rn(acc[jj] - bf16f(hi));
    }
}

__global__ __launch_bounds__(256)
void prep_dec_fc_w(const float* __restrict__ fcW, unsigned short* __restrict__ Wt)
{
    const int d = blockIdx.x;   // 0..127
    unsigned short* dst = Wt + (size_t)(256 + (d >> 4)) * DEC_TILE_H + (d & 15) * DEC_COL_H;
    for (int k = threadIdx.x; k < HH; k += 256) {
        const float w = fcW[(size_t)d * HH + k];
        const unsigned short hi = bf16_rn(w);
        dst[k] = hi;
        dst[1032 + k] = bf16_rn(w - bf16f(hi));
    }
}

__global__ __launch_bounds__(256)
void prep_bias(const float* __restrict__ ebi, const float* __restrict__ ebh,
               const float* __restrict__ dbi, const float* __restrict__ dbh,
               const float* __restrict__ dWih, const float* __restrict__ fcb,
               float* __restrict__ benc, float* __restrict__ bdec,
               float* __restrict__ dec_b_orig)
{
    const int idx = blockIdx.x * 256 + threadIdx.x;   // grid 17 -> 4352
    if (idx < G4) {
        const int orig = ((idx & 3) << 10) | (idx >> 2);
        benc[idx] = ebi[orig] + ebh[orig];
        float a = dbi[orig] + dbh[orig];
        const float* wr = dWih + (size_t)orig * DXX;
        for (int d = 0; d < DXX; ++d) a += wr[d] * fcb[d];
        bdec[idx] = a;
        dec_b_orig[idx] = dbi[idx] + dbh[idx];
    } else if (idx < G4 + DXX) {
        bdec[idx] = fcb[idx - G4];
    }
}

__global__ __launch_bounds__(256)
void prep_src(const float* __restrict__ src, unsigned short* __restrict__ so, int n)
{
    const int idx = blockIdx.x * 256 + threadIdx.x;   // (b,s,d)
    if (idx < n) {
        const int b = idx >> 15, s = (idx >> 7) & 255, d = idx & 127;
        const float v = src[idx];
        const unsigned short hi = bf16_rn(v);
        unsigned short* dst = so + ((size_t)s * 64 + b) * 256 + d;
        dst[0]   = hi;
        dst[128] = bf16_rn(v - bf16f(hi));
    }
}

__global__ __launch_bounds__(256)
void init_fast(float* __restrict__ c, unsigned short* __restrict__ h0,
               float* __restrict__ out)
{
    const int idx = blockIdx.x * 256 + threadIdx.x;   // grid 800 -> 204800
    if (idx < BB * HH) c[idx] = 0.f;
    else if (idx < BB * HH + BB * 2048) h0[idx - BB * HH] = 0;
    else {
        const int r = idx - (BB * HH + BB * 2048);
        if (r < BB * DXX) out[(size_t)(r >> 7) * OUT_BSTRIDE + (r & 127)] = 0.f;
    }
}

// ---------------- round-1 fp32 kernels (dec step 0 + fallback) ----------------
__global__ __launch_bounds__(256)
void step_kernel(const float* __restrict__ W, const float* __restrict__ Wx,
                 const float* __restrict__ x, int xstride,
                 const float* __restrict__ bias,
                 const float* __restrict__ h_in, float* __restrict__ c,
                 float* __restrict__ h_out, int nGates,
                 const float* __restrict__ fcW, const float* __restrict__ fcb,
                 float* __restrict__ fc_out, float* __restrict__ predbuf,
                 unsigned short* __restrict__ ohcomb)
{
    __shared__ float hT[KC][BB + 1];
    __shared__ float wl[16][KC];

    const int t   = threadIdx.x;
    const int b   = t & 63;
    const int q   = t >> 6;
    const int col = t & (KC - 1);
    const int r0  = t >> 7;
    const int bi  = blockIdx.x;

    if (bi < nGates) {
        const int n0 = bi * 4;
        const int n  = n0 + q;
        float a0 = bias[n];
        float a1 = bias[HH + n];
        float a2 = bias[2 * HH + n];
        float a3 = bias[3 * HH + n];

        for (int k0 = 0; k0 < HH; k0 += KC) {
            #pragma unroll
            for (int rr = 0; rr < BB; rr += 2)
                hT[col][rr + r0] = h_in[(rr + r0) * HH + k0 + col];
            #pragma unroll
            for (int rr = 0; rr < 16; rr += 2) {
                const int r = rr + r0;
                const int j = (r & 3) * HH + n0 + (r >> 2);
                wl[r][col] = W[(size_t)j * HH + k0 + col];
            }
            __syncthreads();
            #pragma unroll 8
            for (int k = 0; k < KC; k += 4) {
                const float4 w0 = *reinterpret_cast<const float4*>(&wl[q * 4 + 0][k]);
                const float4 w1 = *reinterpret_cast<const float4*>(&wl[q * 4 + 1][k]);
                const float4 w2 = *reinterpret_cast<const float4*>(&wl[q * 4 + 2][k]);
                const float4 w3 = *reinterpret_cast<const float4*>(&wl[q * 4 + 3][k]);
                const float h0v = hT[k][b], h1v = hT[k + 1][b];
                const float h2v = hT[k + 2][b], h3v = hT[k + 3][b];
                a0 += h0v * w0.x + h1v * w0.y + h2v * w0.z + h3v * w0.w;
                a1 += h0v * w1.x + h1v * w1.y + h2v * w1.z + h3v * w1.w;
                a2 += h0v * w2.x + h1v * w2.y + h2v * w2.z + h3v * w2.w;
                a3 += h0v * w3.x + h1v * w3.y + h2v * w3.z + h3v * w3.w;
            }
            __syncthreads();
        }

        if (Wx != nullptr) {
            #pragma unroll
            for (int rr = 0; rr < BB; rr += 2)
                hT[col][rr + r0] = x[(size_t)(rr + r0) * xstride + col];
            #pragma unroll
            for (int rr = 0; rr < 16; rr += 2) {
                const int r = rr + r0;
                const int j = (r & 3) * HH + n0 + (r >> 2);
                wl[r][col] = Wx[(size_t)j * DXX + col];
            }
            __syncthreads();
            #pragma unroll 8
            for (int k = 0; k < DXX; k += 4) {
                const float4 w0 = *reinterpret_cast<const float4*>(&wl[q * 4 + 0][k]);
                const float4 w1 = *reinterpret_cast<const float4*>(&wl[q * 4 + 1][k]);
                const float4 w2 = *reinterpret_cast<const float4*>(&wl[q * 4 + 2][k]);
                const float4 w3 = *reinterpret_cast<const float4*>(&wl[q * 4 + 3][k]);
                const float h0v = hT[k][b], h1v = hT[k + 1][b];
                const float h2v = hT[k + 2][b], h3v = hT[k + 3][b];
                a0 += h0v * w0.x + h1v * w0.y + h2v * w0.z + h3v * w0.w;
                a1 += h0v * w1.x + h1v * w1.y + h2v * w1.z + h3v * w1.w;
                a2 += h0v * w2.x + h1v * w2.y + h2v * w2.z + h3v * w2.w;
                a3 += h0v * w3.x + h1v * w3.y + h2v * w3.z + h3v * w3.w;
            }
        }

        const int ci = b * HH + n;
        const float iv = sigm(a0);
        const float fv = sigm(a1);
        const float gv = tanh_f(a2);
        const float ov = sigm(a3);
        const float cv = fv * c[ci] + iv * gv;
        c[ci]     = cv;
        const float hv = ov * tanh_f(cv);
        h_out[ci] = hv;
        if (ohcomb) {
            const unsigned short hh = bf16_rn(hv);
            ohcomb[b * 2048 + n] = hh;
            ohcomb[b * 2048 + 1024 + n] = bf16_rn(hv - bf16f(hh));
        }
    } else if (fcW != nullptr && bi < nGates + 32) {
        const int d0 = (bi - nGates) * 4;
        float a = 0.f;
        for (int k0 = 0; k0 < HH; k0 += KC) {
            #pragma unroll
            for (int rr = 0; rr < BB; rr += 2)
                hT[col][rr + r0] = h_in[(rr + r0) * HH + k0 + col];
            #pragma unroll
            for (int rr = 0; rr < 4; rr += 2)
                wl[rr + r0][col] = fcW[(size_t)(d0 + rr + r0) * HH + k0 + col];
            __syncthreads();
            #pragma unroll 8
            for (int k = 0; k < KC; k += 4) {
                const float4 w0 = *reinterpret_cast<const float4*>(&wl[q][k]);
                const float h0v = hT[k][b], h1v = hT[k + 1][b];
                const float h2v = hT[k + 2][b], h3v = hT[k + 3][b];
                a += h0v * w0.x + h1v * w0.y + h2v * w0.z + h3v * w0.w;
            }
            __syncthreads();
        }
        const int d = d0 + q;
        a += fcb[d];
        if (fc_out)  fc_out[(size_t)b * OUT_BSTRIDE + d] = a;
        if (predbuf) predbuf[b * DXX + d] = a;
    }
}

__global__ __launch_bounds__(256)
void bias_prep(const float* __restrict__ ebi, const float* __restrict__ ebh,
               const float* __restrict__ dbi, const float* __restrict__ dbh,
               const float* __restrict__ dWih, const float* __restrict__ fcbv,
               float* __restrict__ enc_b, float* __restrict__ dec_b, float* __restrict__ bcomb)
{
    __shared__ float fb[DXX];
    const int t = threadIdx.x;
    const int j = blockIdx.x * 256 + t;
    if (t < DXX) fb[t] = fcbv[t];
    __syncthreads();
    enc_b[j] = ebi[j] + ebh[j];
    const float db = dbi[j] + dbh[j];
    dec_b[j] = db;
    float acc = db;
    const float* wr = dWih + (size_t)j * DXX;
    for (int d = 0; d < DXX; d += 4) {
        const float4 w = *reinterpret_cast<const float4*>(&wr[d]);
        acc += w.x * fb[d] + w.y * fb[d + 1] + w.z * fb[d + 2] + w.w * fb[d + 3];
    }
    bcomb[j] = acc;
}

__global__ __launch_bounds__(256)
void wcomb_kernel(const float* __restrict__ dWhh, const float* __restrict__ dWih,
                  const float* __restrict__ fcW, float* __restrict__ Wcomb)
{
    const int bi = blockIdx.x;
    const int j0 = (bi >> 2) * 8;
    const int n  = (bi & 3) * 256 + threadIdx.x;
    __shared__ float wih[8][DXX];
    for (int i = threadIdx.x; i < 8 * DXX; i += 256)
        wih[i >> 7][i & 127] = dWih[(size_t)(j0 + (i >> 7)) * DXX + (i & 127)];
    __syncthreads();
    float acc[8];
    #pragma unroll
    for (int jj = 0; jj < 8; ++jj) acc[jj] = dWhh[(size_t)(j0 + jj) * HH + n];
    for (int d = 0; d < DXX; ++d) {
        const float fv = fcW[(size_t)d * HH + n];
        #pragma unroll
        for (int jj = 0; jj < 8; ++jj) acc[jj] += wih[jj][d] * fv;
    }
    #pragma unroll
    for (int jj = 0; jj < 8; ++jj) Wcomb[(size_t)(j0 + jj) * HH + n] = acc[jj];
}

__global__ __launch_bounds__(256)
void init_kernel(float* __restrict__ h0, float* __restrict__ c, float* __restrict__ out)
{
    const int idx = blockIdx.x * 256 + threadIdx.x;
    if (idx < BB * HH) h0[idx] = 0.f;
    else if (idx < 2 * BB * HH) c[idx - BB * HH] = 0.f;
    else {
        const int r = idx - 2 * BB * HH;
        if (r < BB * DXX) out[(size_t)(r >> 7) * OUT_BSTRIDE + (r & 127)] = 0.f;
    }
}

// ---------------- host ----------------
extern "C" void kernel_launch(void* const* d_in, const int* in_sizes, int n_in,
                              void* d_out, int out_size, void* d_ws, size_t ws_size,
                              hipStream_t stream) {
    const float* src   = (const float*)d_in[0];
    const float* trg   = (const float*)d_in[1];
    const float* eWih  = (const float*)d_in[2];
    const float* eWhh  = (const float*)d_in[3];
    const float* ebih  = (const float*)d_in[4];
    const float* ebhh  = (const float*)d_in[5];
    const float* dWih  = (const float*)d_in[6];
    const float* dWhh  = (const float*)d_in[7];
    const float* dbih  = (const float*)d_in[8];
    const float* dbhh  = (const float*)d_in[9];
    const float* fcW   = (const float*)d_in[10];
    const float* fcb   = (const float*)d_in[11];
    float* out = (float*)d_out;

    uintptr_t base = (uintptr_t)d_ws;
    size_t off = 0;
    auto alloc = [&](size_t bytes) -> void* {
        void* p = (void*)(base + off);
        off = (off + bytes + 255) & ~(size_t)255;
        return p;
    };
    unsigned short* Hc[2];
    Hc[0] = (unsigned short*)alloc(BB * 2048 * 2);
    Hc[1] = (unsigned short*)alloc(BB * 2048 * 2);
    float* hf32A = (float*)alloc(BB * HH * 4);
    float* hf32B = (float*)alloc(BB * HH * 4);
    float* c     = (float*)alloc(BB * HH * 4);
    float* benc  = (float*)alloc(G4 * 4);
    float* bdec  = (float*)alloc((G4 + DXX) * 4);
    float* dec_b_orig = (float*)alloc(G4 * 4);
    unsigned short* Wenc = (unsigned short*)alloc((size_t)256 * ENC_TILE_H * 2);
    unsigned short* Wdec = (unsigned short*)alloc((size_t)264 * DEC_TILE_H * 2);
    unsigned short* srcp = (unsigned short*)alloc((size_t)SEQN * 64 * 256 * 2);
    const bool fastok = (off <= ws_size);

    if (fastok) {
        init_fast<<<800, 256, 0, stream>>>(c, Hc[0], out);
        prep_enc_w<<<G4, 256, 0, stream>>>(eWhh, eWih, Wenc);
        prep_dec_w<<<2048, 256, 0, stream>>>(dWhh, dWih, fcW, Wdec);
        prep_dec_fc_w<<<DXX, 256, 0, stream>>>(fcW, Wdec);
        prep_bias<<<17, 256, 0, stream>>>(ebih, ebhh, dbih, dbhh, dWih, fcb,
                                          benc, bdec, dec_b_orig);
        prep_src<<<8192, 256, 0, stream>>>(src, srcp, BB * SEQN * DXX);

        int cur = 0;
        for (int s = 0; s < SEQN; ++s) {
            enc_step<<<256, 1024, ENC_LDS_SZ, stream>>>(
                Wenc, Hc[cur], srcp + (size_t)s * 64 * 256, benc, c, Hc[cur ^ 1],
                (s == SEQN - 1) ? hf32A : nullptr);
            cur ^= 1;
        }
        // decoder step 0 (input = trg[:,0,:]) via fp32 kernel
        step_kernel<<<256, 256, 0, stream>>>(dWhh, dWih, trg, TN * DXX, dec_b_orig,
                                             hf32A, c, hf32B, 256,
                                             nullptr, nullptr, nullptr, nullptr,
                                             Hc[cur ^ 1]);
        cur ^= 1;
        for (int tt = 1; tt <= TN - 2; ++tt) {
            dec_step<<<256, 1024, DEC_LDS_SZ, stream>>>(
                Wdec, Hc[cur], bdec, c, Hc[cur ^ 1], out + (size_t)tt * DXX, 0);
            cur ^= 1;
        }
        dec_step<<<256, 1024, DEC_LDS_SZ, stream>>>(
            Wdec, Hc[cur], bdec, c, Hc[cur ^ 1], out + (size_t)(TN - 1) * DXX, 1);
        return;
    }

    // ---- fallback: round-1 fp32 path ----
    float* ws  = (float*)d_ws;
    float* h0     = ws;
    float* h1     = ws + 65536;
    float* cF     = ws + 131072;
    float* pred   = ws + 196608;
    float* enc_b  = ws + 204800;
    float* dec_b  = ws + 208896;
    float* bcomb  = ws + 212992;
    float* Wcomb  = ws + 217088;
    const bool use_comb = ws_size >= (size_t)(217088 + 4096 * 1024) * sizeof(float);

    init_kernel<<<544, 256, 0, stream>>>(h0, cF, out);
    bias_prep<<<16, 256, 0, stream>>>(ebih, ebhh, dbih, dbhh, dWih, fcb, enc_b, dec_b, bcomb);
    if (use_comb)
        wcomb_kernel<<<2048, 256, 0, stream>>>(dWhh, dWih, fcW, Wcomb);

    float* hc = h0;
    float* hn = h1;
    for (int s = 0; s < SEQN; ++s) {
        step_kernel<<<256, 256, 0, stream>>>(eWhh, eWih, src + s * DXX, SEQN * DXX,
                                             enc_b, hc, cF, hn, 256,
                                             nullptr, nullptr, nullptr, nullptr, nullptr);
        float* tmp = hc; hc = hn; hn = tmp;
    }
    step_kernel<<<256, 256, 0, stream>>>(dWhh, dWih, trg, TN * DXX,
                                         dec_b, hc, cF, hn, 256,
                                         nullptr, nullptr, nullptr, nullptr, nullptr);
    { float* tmp = hc; hc = hn; hn = tmp; }

    if (use_comb) {
        for (int tt = 1; tt <= TN - 2; ++tt) {
            step_kernel<<<288, 256, 0, stream>>>(Wcomb, nullptr, nullptr, 0,
                                                 bcomb, hc, cF, hn, 256,
                                                 fcW, fcb, out + (size_t)tt * DXX, nullptr,
                                                 nullptr);
            float* tmp = hc; hc = hn; hn = tmp;
        }
    } else {
        for (int tt = 1; tt <= TN - 2; ++tt) {
            step_kernel<<<32, 256, 0, stream>>>(nullptr, nullptr, nullptr, 0,
                                                nullptr, hc, nullptr, nullptr, 0,
                                                fcW, fcb, out + (size_t)tt * DXX, pred,
                                                nullptr);
            step_kernel<<<256, 256, 0, stream>>>(dWhh, dWih, pred, DXX,
                                                 dec_b, hc, cF, hn, 256,
                                                 nullptr, nullptr, nullptr, nullptr, nullptr);
            float* tmp = hc; hc = hn; hn = tmp;
        }
    }
    step_kernel<<<32, 256, 0, stream>>>(nullptr, nullptr, nullptr, 0,
                                        nullptr, hc, nullptr, nullptr, 0,
                                        fcW, fcb, out + (size_t)(TN - 1) * DXX, nullptr,
                                        nullptr);
}